// Round 8
// baseline (746.451 us; speedup 1.0000x reference)
//
#include <hip/hip_runtime.h>
#include <math.h>

#define BB 2
#define TT 2048
#define DD 1024
#define NTHREADS 256

#define RT 32               // rows per score tile
#define CT 128              // cols per score tile (= top-K window width)
#define DC 32               // d-halves per chunk = 1 MFMA K-step
#define NCHUNK (DD / DC)    // 32
#define NJC (TT / CT)       // 16 windows per row
#define KMAX 16
#define CST 132             // score-tile stride: 4 mod 32 -> 2-way (free) scans
#define NTILES 544          // causal 32x128 tiles per batch: sum_{it<64}(it/4+1)
#define PLANE ((uint32_t)(BB * TT * DD))   // halves per plane (hi->lo offset)

typedef _Float16 half8  __attribute__((ext_vector_type(8)));
typedef _Float16 half4v __attribute__((ext_vector_type(4)));
typedef float    float4v __attribute__((ext_vector_type(4)));

__device__ __forceinline__ float gelu_exact(float t) {
    return 0.5f * t * (1.0f + erff(t * 0.70710678118654752f));
}

// ---- Kernel P: split fp32 h into fp16 hi/lo planes (round 0 only) -------
__global__ __launch_bounds__(NTHREADS) void split_kernel(
    const float* __restrict__ h,
    _Float16* __restrict__ hiP,
    _Float16* __restrict__ loP)
{
    const int idx = blockIdx.x * NTHREADS + threadIdx.x;
    const float4 v = ((const float4*)h)[idx];
    const float xs[4] = {v.x, v.y, v.z, v.w};
    half4v hi, lo;
    #pragma unroll
    for (int u = 0; u < 4; ++u) {
        const _Float16 hh = (_Float16)xs[u];
        hi[u] = hh;
        lo[u] = (_Float16)(xs[u] - (float)hh);
    }
    ((half4v*)hiP)[idx] = hi;
    ((half4v*)loP)[idx] = lo;
}

// ---- Kernel S: causal 32x128 score tile, direct global->VGPR MFMA, barrier-free ----
// 1088 blocks (4.25/CU) for latency hiding; per-wave 16x64 subtile, 10 frags/step.
__global__ __launch_bounds__(NTHREADS, 4) void score_topk_kernel(
    const _Float16* __restrict__ hiP,   // loP = hiP + PLANE
    float* __restrict__ pval,   // (B,T,NJC,KMAX)
    int*   __restrict__ pidx,   // (B,T,NJC,KMAX)
    int K)
{
    __shared__ __align__(16) float scores[RT * CST];   // 16896 B, only LDS use

    // triangular decode: p -> (it, jc); it in [0,64), jc in [0, it/4]
    const int b = blockIdx.y;
    const int p = blockIdx.x;
    int g = (int)(0.5f * (sqrtf(2.0f * (float)p + 1.0f) - 1.0f));
    while (2 * (g + 1) * (g + 2) <= p) ++g;
    while (2 * g * (g + 1) > p) --g;
    const int qq = p - 2 * g * (g + 1);
    const int it = 4 * g + qq / (g + 1);
    const int jc = qq % (g + 1);
    const int i0 = it * RT, j0 = jc * CT;

    const int tid  = threadIdx.x;
    const int lane = tid & 63, wave = tid >> 6;
    const int wr = wave & 1, wc = wave >> 1;   // 16-row band, 64-col half
    const int rA  = lane & 15;          // row within band
    const int oct = lane >> 4;          // k-octet (8 halves = 16 B)

    // 10 fragment base pointers: A hi/lo (t=0,1), B (t=2+2*cb+pl)
    const _Float16* fp[10];
    {
        #pragma unroll
        for (int t = 0; t < 2; ++t)
            fp[t] = hiP + (uint32_t)(t) * PLANE
                  + (uint32_t)(b * TT + i0 + 16 * wr + rA) * DD + oct * 8;
        #pragma unroll
        for (int t = 0; t < 8; ++t) {
            const int cb = t >> 1; const uint32_t pl = t & 1;
            fp[2 + t] = hiP + pl * PLANE
                      + (uint32_t)(b * TT + j0 + 64 * wc + 16 * cb + rA) * DD + oct * 8;
        }
    }

    float4v acc[4];
    #pragma unroll
    for (int cb = 0; cb < 4; ++cb) acc[cb] = (float4v){0.f, 0.f, 0.f, 0.f};

    // 2-step ping-pong, 20 b128 in flight; chunk offsets are 13-bit immediates
    half8 buf0[10], buf1[10];
    #pragma unroll
    for (int t = 0; t < 10; ++t) buf0[t] = *(const half8*)(fp[t]);

#define MFMA_STEP(BUF) do {                                                          \
    _Pragma("unroll")                                                                \
    for (int cb_ = 0; cb_ < 4; ++cb_) {                                              \
        acc[cb_] = __builtin_amdgcn_mfma_f32_16x16x32_f16(                           \
            BUF[0], BUF[2 + 2*cb_],     acc[cb_], 0, 0, 0);                          \
        acc[cb_] = __builtin_amdgcn_mfma_f32_16x16x32_f16(                           \
            BUF[0], BUF[2 + 2*cb_ + 1], acc[cb_], 0, 0, 0);                          \
        acc[cb_] = __builtin_amdgcn_mfma_f32_16x16x32_f16(                           \
            BUF[1], BUF[2 + 2*cb_],     acc[cb_], 0, 0, 0);                          \
    } } while (0)

    for (int c = 0; c < NCHUNK; c += 2) {
        #pragma unroll
        for (int t = 0; t < 10; ++t) buf1[t] = *(const half8*)(fp[t] + (c + 1) * DC);
        MFMA_STEP(buf0);
        if (c + 2 < NCHUNK) {
            #pragma unroll
            for (int t = 0; t < 10; ++t) buf0[t] = *(const half8*)(fp[t] + (c + 2) * DC);
        }
        MFMA_STEP(buf1);
    }
#undef MFMA_STEP

    // masked score tile into LDS. C/D: col = lane&15, row = (lane>>4)*4 + reg
    {
        const int qn = lane >> 4, rn = lane & 15;
        #pragma unroll
        for (int cb = 0; cb < 4; ++cb)
            #pragma unroll
            for (int reg = 0; reg < 4; ++reg) {
                const int i_loc = 16 * wr + qn * 4 + reg;
                const int j_loc = 64 * wc + 16 * cb + rn;
                scores[i_loc * CST + j_loc] =
                    (j0 + j_loc <= i0 + i_loc) ? acc[cb][reg] : -INFINITY;
            }
    }
    __syncthreads();   // the ONLY barrier in this kernel

    // per-window top-K: 8 threads/row (same wave), 16 candidates in registers,
    // dead-bitmask zap, 3-step shfl_xor merge — no barriers.
    const int rloc = tid >> 3, seg = tid & 7;
    const float* Crow = scores + rloc * CST;
    float vals[16];
    #pragma unroll
    for (int cc = 0; cc < 16; ++cc) vals[cc] = Crow[seg + 8 * cc];

    uint32_t dead = 0;
    const int irow = i0 + rloc;
    const size_t obase = ((size_t)(b * TT + irow) * NJC + jc) * KMAX;
    for (int k = 0; k < K; ++k) {
        float bv = -INFINITY; int bcc = -1;
        #pragma unroll
        for (int cc = 0; cc < 16; ++cc) {
            const bool alive = ((dead >> cc) & 1u) == 0u;
            if (alive && vals[cc] > bv) { bv = vals[cc]; bcc = cc; }
        }
        const int bcol = (bcc >= 0) ? (seg + 8 * bcc) : -1;
        float wv = bv; int wcol = bcol;
        #pragma unroll
        for (int m = 1; m < 8; m <<= 1) {
            const float ov = __shfl_xor(wv, m, 64);
            const int   oc = __shfl_xor(wcol, m, 64);
            if (ov > wv || (ov == wv && (unsigned)oc < (unsigned)wcol)) { wv = ov; wcol = oc; }
        }
        if (seg == 0) {
            pval[obase + k] = wv;
            pidx[obase + k] = (wcol >= 0) ? (j0 + wcol) : -1;
        }
        if (bcc >= 0 && wcol == bcol) dead |= (1u << bcc);
    }
}

// ---- Kernel T: merge window top-Ks (wave0, barrier-free), gather, epilogue ----
template<int K>
__global__ __launch_bounds__(NTHREADS) void merge_agg_kernel(
    const float* __restrict__ h_in,
    float* __restrict__ h_out,
    const float* __restrict__ pval,
    const int*   __restrict__ pidx,
    const float* __restrict__ gain,
    const float* __restrict__ bias,
    const float* __restrict__ log_mix_r,
    const float* __restrict__ log_momentum,
    const float* __restrict__ xres,       // non-null => fused (h-x)*scale
    const float* __restrict__ log_scale,
    _Float16* __restrict__ hiO,           // non-null => emit fp16 planes of h_out
    _Float16* __restrict__ loO)
{
    constexpr int KL = (K == 4) ? 2 : (K == 8) ? 3 : 4;
    __shared__ int s_sel[KMAX];

    const int row = blockIdx.x, b = row / TT, i = row % TT;
    const int tid = threadIdx.x, lane = tid & 63, wave = tid >> 6;
    const float* hb = h_in + (size_t)b * TT * DD;

    const int count = (i + 1 < K) ? (i + 1) : K;

    if (wave == 0) {
        const int jcn = i / CT + 1;
        const int ncand = jcn * K;          // <= 256
        float cv[4]; int cj[4];
        const size_t rb_ = (size_t)(b * TT + i) * NJC;
        #pragma unroll
        for (int q = 0; q < 4; ++q) {
            const int ci = lane + 64 * q;
            cv[q] = -INFINITY; cj[q] = -1;
            if (ci < ncand) {
                const int w = ci >> KL, k = ci & (K - 1);
                const size_t base = (rb_ + w) * KMAX + k;
                const int j = pidx[base];
                if (j >= 0) { cj[q] = j; cv[q] = pval[base]; }
            }
        }
        uint32_t dead = 0;
        for (int k = 0; k < count; ++k) {
            float bv = -INFINITY; int bq = -1, bj = -1;
            #pragma unroll
            for (int q = 0; q < 4; ++q) {
                const bool alive = ((dead >> q) & 1u) == 0u;
                if (alive && (cv[q] > bv || (cv[q] == bv && (unsigned)cj[q] < (unsigned)bj))) {
                    bv = cv[q]; bj = cj[q]; bq = q;
                }
            }
            float wv = bv; int wj = bj;
            #pragma unroll
            for (int m = 1; m < 64; m <<= 1) {
                const float ov = __shfl_xor(wv, m, 64);
                const int   oj = __shfl_xor(wj, m, 64);
                if (ov > wv || (ov == wv && (unsigned)oj < (unsigned)wj)) { wv = ov; wj = oj; }
            }
            if (lane == 0) s_sel[k] = wj;
            if (bq >= 0 && wj == bj) dead |= (1u << bq);
        }
    }

    // independent operand loads hoisted before the barrier
    const float4 hi = ((const float4*)(hb + (size_t)i * DD))[tid];
    const float4 g4 = ((const float4*)gain)[tid];
    const float4 c4 = ((const float4*)bias)[tid];
    __syncthreads();   // s_sel visible

    const float mix      = 1.0f / (1.0f + expf(-log_mix_r[0]));
    const float momentum = 1.0f / (1.0f + expf(-log_momentum[0]));
    const float inv_cnt  = 1.0f / (float)count;

    float4 msg = make_float4(0.f, 0.f, 0.f, 0.f);
    if (count == K) {   // common path: fully unrolled, all K gathers in flight
        #pragma unroll
        for (int k = 0; k < K; ++k) {
            const float4 v = ((const float4*)(hb + (size_t)s_sel[k] * DD))[tid];
            msg.x += v.x; msg.y += v.y; msg.z += v.z; msg.w += v.w;
        }
    } else {
        for (int k = 0; k < count; ++k) {
            const float4 v = ((const float4*)(hb + (size_t)s_sel[k] * DD))[tid];
            msg.x += v.x; msg.y += v.y; msg.z += v.z; msg.w += v.w;
        }
    }

    float4 o;
    {
        float m, t;
        m = msg.x * inv_cnt; t = (mix * hi.x + (1.f - mix) * m) * g4.x + c4.x;
        o.x = momentum * hi.x + (1.f - momentum) * gelu_exact(t);
        m = msg.y * inv_cnt; t = (mix * hi.y + (1.f - mix) * m) * g4.y + c4.y;
        o.y = momentum * hi.y + (1.f - momentum) * gelu_exact(t);
        m = msg.z * inv_cnt; t = (mix * hi.z + (1.f - mix) * m) * g4.z + c4.z;
        o.z = momentum * hi.z + (1.f - momentum) * gelu_exact(t);
        m = msg.w * inv_cnt; t = (mix * hi.w + (1.f - mix) * m) * g4.w + c4.w;
        o.w = momentum * hi.w + (1.f - momentum) * gelu_exact(t);
    }

    if (hiO != nullptr) {   // planes of h_next (pre-finalize value)
        const float os[4] = {o.x, o.y, o.z, o.w};
        half4v hv, lv;
        #pragma unroll
        for (int u = 0; u < 4; ++u) {
            const _Float16 hh = (_Float16)os[u];
            hv[u] = hh;
            lv[u] = (_Float16)(os[u] - (float)hh);
        }
        const size_t vidx = (size_t)row * (DD / 4) + tid;
        ((half4v*)hiO)[vidx] = hv;
        ((half4v*)loO)[vidx] = lv;
    }

    if (xres != nullptr) {
        const float scale = log1pf(expf(log_scale[0])) + 0.01f;
        const float4 xv = ((const float4*)(xres + (size_t)row * DD))[tid];
        o.x = (o.x - xv.x) * scale;
        o.y = (o.y - xv.y) * scale;
        o.z = (o.z - xv.z) * scale;
        o.w = (o.w - xv.w) * scale;
    }
    ((float4*)(h_out + (size_t)row * DD))[tid] = o;
}

extern "C" void kernel_launch(void* const* d_in, const int* in_sizes, int n_in,
                              void* d_out, int out_size, void* d_ws, size_t ws_size,
                              hipStream_t stream) {
    const float* x            = (const float*)d_in[0];
    const float* gain         = (const float*)d_in[1];
    const float* bias         = (const float*)d_in[2];
    const float* log_mix      = (const float*)d_in[3];
    const float* log_momentum = (const float*)d_in[4];
    const float* log_scale    = (const float*)d_in[5];
    float* out = (float*)d_out;

    // ws: h (16.78 MB) | pval (4.19) | pidx (4.19) | hiP (8.39) | loP (8.39, contiguous)
    char* wsb = (char*)d_ws;
    float*     h_ws = (float*)wsb;
    float*     pval = (float*)(wsb + (size_t)BB * TT * DD * 4);
    int*       pidx = (int*)  (wsb + (size_t)BB * TT * DD * 4 + (size_t)BB * TT * NJC * KMAX * 4);
    _Float16*  hiP  = (_Float16*)(wsb + (size_t)BB * TT * DD * 4 + (size_t)BB * TT * NJC * KMAX * 8);
    _Float16*  loP  = hiP + (size_t)PLANE;   // must stay contiguous (score kernel offsets)

    const dim3 sgrid(NTILES, BB);
    const int nsplit = BB * TT * DD / 4 / NTHREADS;

    // round 0: x -> out (merge emits planes of h1)
    split_kernel<<<nsplit, NTHREADS, 0, stream>>>(x, hiP, loP);
    score_topk_kernel<<<sgrid, NTHREADS, 0, stream>>>(hiP, pval, pidx, 4);
    merge_agg_kernel<4><<<BB * TT, NTHREADS, 0, stream>>>(
        x, out, pval, pidx, gain + 0 * DD, bias + 0 * DD, log_mix + 0, log_momentum,
        nullptr, nullptr, hiP, loP);
    // round 1: out -> h_ws (merge emits planes of h2)
    score_topk_kernel<<<sgrid, NTHREADS, 0, stream>>>(hiP, pval, pidx, 8);
    merge_agg_kernel<8><<<BB * TT, NTHREADS, 0, stream>>>(
        out, h_ws, pval, pidx, gain + 1 * DD, bias + 1 * DD, log_mix + 1, log_momentum,
        nullptr, nullptr, hiP, loP);
    // round 2 (fused finalize): h_ws -> out
    score_topk_kernel<<<sgrid, NTHREADS, 0, stream>>>(hiP, pval, pidx, 16);
    merge_agg_kernel<16><<<BB * TT, NTHREADS, 0, stream>>>(
        h_ws, out, pval, pidx, gain + 2 * DD, bias + 2 * DD, log_mix + 2, log_momentum,
        x, log_scale, nullptr, nullptr);
}

// Round 9
// 416.744 us; speedup vs baseline: 1.7912x; 1.7912x over previous
//
#include <hip/hip_runtime.h>
#include <math.h>

#define BB 2
#define TT 2048
#define DD 1024
#define NTHREADS 256

#define RT 64               // rows per score tile
#define CT 128              // cols per score tile (= top-K window width)
#define DC 32               // d-halves per chunk = 1 MFMA K-step
#define NCHUNK (DD / DC)    // 32
#define NJC (TT / CT)       // 16 windows per row
#define KMAX 16
#define CST 132             // score-tile stride: 4 mod 32 -> 2-way (free) scans
#define NTILES 272          // causal 64x128 tiles per batch
#define PLANE ((uint32_t)(BB * TT * DD))   // halves per plane (hi->lo offset)
#define HBUF 12288          // halves per staging buffer (24 KB)

typedef _Float16 half8  __attribute__((ext_vector_type(8)));
typedef _Float16 half4v __attribute__((ext_vector_type(4)));
typedef float    float4v __attribute__((ext_vector_type(4)));

#define GLD16(gp, lp) __builtin_amdgcn_global_load_lds(                         \
    (const __attribute__((address_space(1))) unsigned int*)(gp),                \
    (__attribute__((address_space(3))) unsigned int*)(lp), 16, 0, 0)

__device__ __forceinline__ float gelu_exact(float t) {
    return 0.5f * t * (1.0f + erff(t * 0.70710678118654752f));
}

// ---- Kernel P: split fp32 h into fp16 hi/lo planes (round 0 only) -------
__global__ __launch_bounds__(NTHREADS) void split_kernel(
    const float* __restrict__ h,
    _Float16* __restrict__ hiP,
    _Float16* __restrict__ loP)
{
    const int idx = blockIdx.x * NTHREADS + threadIdx.x;
    const float4 v = ((const float4*)h)[idx];
    const float xs[4] = {v.x, v.y, v.z, v.w};
    half4v hi, lo;
    #pragma unroll
    for (int u = 0; u < 4; ++u) {
        const _Float16 hh = (_Float16)xs[u];
        hi[u] = hh;
        lo[u] = (_Float16)(xs[u] - (float)hh);
    }
    ((half4v*)hiP)[idx] = hi;
    ((half4v*)loP)[idx] = lo;
}

// ---- Kernel S: causal 64x128 score tile, DMA-staged split-fp16 MFMA,
//      double-buffered (1 barrier/chunk), register top-K (barrier-free) ----
// Staging buffer layout (granule = 16 B = 8 halves, fragment-lane order):
//   A-hi granules [0,256), A-lo [256,512), B-hi [512,1024), B-lo [1024,1536).
//   granule g: row = 16*band + (g&15), k-oct = (g>>4)&3; band = g>>6 within region.
__global__ __launch_bounds__(NTHREADS) void score_topk_kernel(
    const _Float16* __restrict__ hiP,   // loP = hiP + PLANE
    float* __restrict__ pval,   // (B,T,NJC,KMAX)
    int*   __restrict__ pidx,   // (B,T,NJC,KMAX)
    int K)
{
    __shared__ __align__(16) char smem_raw[49152];  // 2x24KB staging / 64x132 f32 scores
    _Float16* sm  = (_Float16*)smem_raw;
    float* scores = (float*)smem_raw;

    // triangular decode: p -> (it, jc); it in [0,32), jc in [0, it/2]
    const int b = blockIdx.y;
    const int p = blockIdx.x;
    int g = (int)(0.5f * (sqrtf(4.0f * (float)p + 1.0f) - 1.0f));
    while ((g + 1) * (g + 2) <= p) ++g;
    while (g * (g + 1) > p) --g;
    const int qq = p - g * (g + 1);
    const int it = 2 * g + qq / (g + 1);
    const int jc = qq % (g + 1);
    const int i0 = it * RT, j0 = jc * CT;

    const int tid  = threadIdx.x;
    const int lane = tid & 63, wave = tid >> 6;
    const int wr = wave & 1, wc = wave >> 1;

    // 6 DMA slots/thread/chunk: granule gr = tid + 256*slot
    uint32_t goff[6];
    #pragma unroll
    for (int slot = 0; slot < 6; ++slot) {
        const int gr = tid + NTHREADS * slot;   // 0..1535
        int n, row; uint32_t pl;
        if (gr < 256)       { n = gr;        pl = 0; row = i0 + 16 * (n >> 6) + (n & 15); }
        else if (gr < 512)  { n = gr - 256;  pl = 1; row = i0 + 16 * (n >> 6) + (n & 15); }
        else if (gr < 1024) { n = gr - 512;  pl = 0; row = j0 + 16 * (n >> 6) + (n & 15); }
        else                { n = gr - 1024; pl = 1; row = j0 + 16 * (n >> 6) + (n & 15); }
        const int oct = (n >> 4) & 3;
        goff[slot] = pl * PLANE + (uint32_t)(b * TT + row) * DD + (uint32_t)oct * 8;
    }

    float4v acc[2][4];
    #pragma unroll
    for (int rb = 0; rb < 2; ++rb)
        #pragma unroll
        for (int cb = 0; cb < 4; ++cb)
            acc[rb][cb] = (float4v){0.f, 0.f, 0.f, 0.f};

    // prologue: DMA chunk 0 into buffer 0
    #pragma unroll
    for (int t = 0; t < 6; ++t)
        GLD16(hiP + goff[t], &sm[(size_t)(tid + NTHREADS * t) * 8]);
    __syncthreads();

    for (int c = 0; c < NCHUNK; ++c) {
        const int cur = (c & 1) ? HBUF : 0;
        const int nxt = HBUF - cur;
        if (c + 1 < NCHUNK) {   // issue DMA for c+1 into nxt (no wait)
            #pragma unroll
            for (int t = 0; t < 6; ++t)
                GLD16(hiP + goff[t] + (c + 1) * DC, &sm[nxt + (size_t)(tid + NTHREADS * t) * 8]);
        }
        // fragments from cur
        half8 ah[2], al[2], bh[4], bl[4];
        #pragma unroll
        for (int rb = 0; rb < 2; ++rb) {
            const int band = 2 * wr + rb;
            ah[rb] = *(const half8*)&sm[cur +        (band * 64 + lane) * 8];
            al[rb] = *(const half8*)&sm[cur + 2048 + (band * 64 + lane) * 8];
        }
        #pragma unroll
        for (int cb = 0; cb < 4; ++cb) {
            const int band = 4 * wc + cb;
            bh[cb] = *(const half8*)&sm[cur + 4096 + (band * 64 + lane) * 8];
            bl[cb] = *(const half8*)&sm[cur + 8192 + (band * 64 + lane) * 8];
        }
        #pragma unroll
        for (int rb = 0; rb < 2; ++rb)
            #pragma unroll
            for (int cb = 0; cb < 4; ++cb) {
                acc[rb][cb] = __builtin_amdgcn_mfma_f32_16x16x32_f16(ah[rb], bh[cb], acc[rb][cb], 0, 0, 0);
                acc[rb][cb] = __builtin_amdgcn_mfma_f32_16x16x32_f16(ah[rb], bl[cb], acc[rb][cb], 0, 0, 0);
                acc[rb][cb] = __builtin_amdgcn_mfma_f32_16x16x32_f16(al[rb], bh[cb], acc[rb][cb], 0, 0, 0);
            }
        __syncthreads();   // drains nxt DMA (after MFMA overlap) + guards cur reuse
    }

    // masked score tile into LDS. C/D: col = lane&15, row = (lane>>4)*4 + reg
    {
        const int qn = lane >> 4, rn = lane & 15;
        #pragma unroll
        for (int rb = 0; rb < 2; ++rb)
            #pragma unroll
            for (int cb = 0; cb < 4; ++cb)
                #pragma unroll
                for (int reg = 0; reg < 4; ++reg) {
                    const int i_loc = 32 * wr + 16 * rb + qn * 4 + reg;
                    const int j_loc = 64 * wc + 16 * cb + rn;
                    scores[i_loc * CST + j_loc] =
                        (j0 + j_loc <= i0 + i_loc) ? acc[rb][cb][reg] : -INFINITY;
                }
    }
    __syncthreads();

    // per-window top-K: 4 threads/row (same wave), 32 candidates in registers,
    // dead-bitmask zap, 2-step shfl_xor quad merge — no barriers.
    const int rloc = tid >> 2, seg = tid & 3;
    const float* Crow = scores + rloc * CST;
    float vals[32];
    #pragma unroll
    for (int cc = 0; cc < 32; ++cc) vals[cc] = Crow[seg + 4 * cc];

    uint32_t dead = 0;
    const int irow = i0 + rloc;
    const size_t obase = ((size_t)(b * TT + irow) * NJC + jc) * KMAX;
    for (int k = 0; k < K; ++k) {
        float bv = -INFINITY; int bcc = -1;
        #pragma unroll
        for (int cc = 0; cc < 32; ++cc) {
            const bool alive = ((dead >> cc) & 1u) == 0u;
            if (alive && vals[cc] > bv) { bv = vals[cc]; bcc = cc; }
        }
        const int bcol = (bcc >= 0) ? (seg + 4 * bcc) : -1;
        float wv = bv; int wcol = bcol;
        #pragma unroll
        for (int m = 1; m < 4; m <<= 1) {
            const float ov = __shfl_xor(wv, m, 64);
            const int   oc = __shfl_xor(wcol, m, 64);
            if (ov > wv || (ov == wv && (unsigned)oc < (unsigned)wcol)) { wv = ov; wcol = oc; }
        }
        if (seg == 0) {
            pval[obase + k] = wv;
            pidx[obase + k] = (wcol >= 0) ? (j0 + wcol) : -1;
        }
        if (bcc >= 0 && wcol == bcol) dead |= (1u << bcc);
    }
}

// ---- Kernel T: merge window top-Ks (wave0, barrier-free), gather, epilogue ----
template<int K>
__global__ __launch_bounds__(NTHREADS) void merge_agg_kernel(
    const float* __restrict__ h_in,
    float* __restrict__ h_out,
    const float* __restrict__ pval,
    const int*   __restrict__ pidx,
    const float* __restrict__ gain,
    const float* __restrict__ bias,
    const float* __restrict__ log_mix_r,
    const float* __restrict__ log_momentum,
    const float* __restrict__ xres,       // non-null => fused (h-x)*scale
    const float* __restrict__ log_scale,
    _Float16* __restrict__ hiO,           // non-null => emit fp16 planes of h_out
    _Float16* __restrict__ loO)
{
    constexpr int KL = (K == 4) ? 2 : (K == 8) ? 3 : 4;
    __shared__ int s_sel[KMAX];

    const int row = blockIdx.x, b = row / TT, i = row % TT;
    const int tid = threadIdx.x, lane = tid & 63, wave = tid >> 6;
    const float* hb = h_in + (size_t)b * TT * DD;

    const int count = (i + 1 < K) ? (i + 1) : K;

    if (wave == 0) {
        const int jcn = i / CT + 1;
        const int ncand = jcn * K;          // <= 256
        float cv[4]; int cj[4];
        const size_t rb_ = (size_t)(b * TT + i) * NJC;
        #pragma unroll
        for (int q = 0; q < 4; ++q) {
            const int ci = lane + 64 * q;
            cv[q] = -INFINITY; cj[q] = -1;
            if (ci < ncand) {
                const int w = ci >> KL, k = ci & (K - 1);
                const size_t base = (rb_ + w) * KMAX + k;
                const int j = pidx[base];
                if (j >= 0) { cj[q] = j; cv[q] = pval[base]; }
            }
        }
        uint32_t dead = 0;
        for (int k = 0; k < count; ++k) {
            float bv = -INFINITY; int bq = -1, bj = -1;
            #pragma unroll
            for (int q = 0; q < 4; ++q) {
                const bool alive = ((dead >> q) & 1u) == 0u;
                if (alive && (cv[q] > bv || (cv[q] == bv && (unsigned)cj[q] < (unsigned)bj))) {
                    bv = cv[q]; bj = cj[q]; bq = q;
                }
            }
            float wv = bv; int wj = bj;
            #pragma unroll
            for (int m = 1; m < 64; m <<= 1) {
                const float ov = __shfl_xor(wv, m, 64);
                const int   oj = __shfl_xor(wj, m, 64);
                if (ov > wv || (ov == wv && (unsigned)oj < (unsigned)wj)) { wv = ov; wj = oj; }
            }
            if (lane == 0) s_sel[k] = wj;
            if (bq >= 0 && wj == bj) dead |= (1u << bq);
        }
    }

    // independent operand loads hoisted before the barrier
    const float4 hi = ((const float4*)(hb + (size_t)i * DD))[tid];
    const float4 g4 = ((const float4*)gain)[tid];
    const float4 c4 = ((const float4*)bias)[tid];
    __syncthreads();   // s_sel visible

    const float mix      = 1.0f / (1.0f + expf(-log_mix_r[0]));
    const float momentum = 1.0f / (1.0f + expf(-log_momentum[0]));
    const float inv_cnt  = 1.0f / (float)count;

    float4 msg = make_float4(0.f, 0.f, 0.f, 0.f);
    if (count == K) {   // common path: fully unrolled, all K gathers in flight
        #pragma unroll
        for (int k = 0; k < K; ++k) {
            const float4 v = ((const float4*)(hb + (size_t)s_sel[k] * DD))[tid];
            msg.x += v.x; msg.y += v.y; msg.z += v.z; msg.w += v.w;
        }
    } else {
        for (int k = 0; k < count; ++k) {
            const float4 v = ((const float4*)(hb + (size_t)s_sel[k] * DD))[tid];
            msg.x += v.x; msg.y += v.y; msg.z += v.z; msg.w += v.w;
        }
    }

    float4 o;
    {
        float m, t;
        m = msg.x * inv_cnt; t = (mix * hi.x + (1.f - mix) * m) * g4.x + c4.x;
        o.x = momentum * hi.x + (1.f - momentum) * gelu_exact(t);
        m = msg.y * inv_cnt; t = (mix * hi.y + (1.f - mix) * m) * g4.y + c4.y;
        o.y = momentum * hi.y + (1.f - momentum) * gelu_exact(t);
        m = msg.z * inv_cnt; t = (mix * hi.z + (1.f - mix) * m) * g4.z + c4.z;
        o.z = momentum * hi.z + (1.f - momentum) * gelu_exact(t);
        m = msg.w * inv_cnt; t = (mix * hi.w + (1.f - mix) * m) * g4.w + c4.w;
        o.w = momentum * hi.w + (1.f - momentum) * gelu_exact(t);
    }

    if (hiO != nullptr) {   // planes of h_next (pre-finalize value)
        const float os[4] = {o.x, o.y, o.z, o.w};
        half4v hv, lv;
        #pragma unroll
        for (int u = 0; u < 4; ++u) {
            const _Float16 hh = (_Float16)os[u];
            hv[u] = hh;
            lv[u] = (_Float16)(os[u] - (float)hh);
        }
        const size_t vidx = (size_t)row * (DD / 4) + tid;
        ((half4v*)hiO)[vidx] = hv;
        ((half4v*)loO)[vidx] = lv;
    }

    if (xres != nullptr) {
        const float scale = log1pf(expf(log_scale[0])) + 0.01f;
        const float4 xv = ((const float4*)(xres + (size_t)row * DD))[tid];
        o.x = (o.x - xv.x) * scale;
        o.y = (o.y - xv.y) * scale;
        o.z = (o.z - xv.z) * scale;
        o.w = (o.w - xv.w) * scale;
    }
    ((float4*)(h_out + (size_t)row * DD))[tid] = o;
}

extern "C" void kernel_launch(void* const* d_in, const int* in_sizes, int n_in,
                              void* d_out, int out_size, void* d_ws, size_t ws_size,
                              hipStream_t stream) {
    const float* x            = (const float*)d_in[0];
    const float* gain         = (const float*)d_in[1];
    const float* bias         = (const float*)d_in[2];
    const float* log_mix      = (const float*)d_in[3];
    const float* log_momentum = (const float*)d_in[4];
    const float* log_scale    = (const float*)d_in[5];
    float* out = (float*)d_out;

    // ws: h (16.78 MB) | pval (4.19) | pidx (4.19) | hiP (8.39) | loP (8.39, contiguous)
    char* wsb = (char*)d_ws;
    float*     h_ws = (float*)wsb;
    float*     pval = (float*)(wsb + (size_t)BB * TT * DD * 4);
    int*       pidx = (int*)  (wsb + (size_t)BB * TT * DD * 4 + (size_t)BB * TT * NJC * KMAX * 4);
    _Float16*  hiP  = (_Float16*)(wsb + (size_t)BB * TT * DD * 4 + (size_t)BB * TT * NJC * KMAX * 8);
    _Float16*  loP  = hiP + (size_t)PLANE;   // must stay contiguous (score kernel offsets)

    const dim3 sgrid(NTILES, BB);
    const int nsplit = BB * TT * DD / 4 / NTHREADS;

    // round 0: x -> out (merge emits planes of h1)
    split_kernel<<<nsplit, NTHREADS, 0, stream>>>(x, hiP, loP);
    score_topk_kernel<<<sgrid, NTHREADS, 0, stream>>>(hiP, pval, pidx, 4);
    merge_agg_kernel<4><<<BB * TT, NTHREADS, 0, stream>>>(
        x, out, pval, pidx, gain + 0 * DD, bias + 0 * DD, log_mix + 0, log_momentum,
        nullptr, nullptr, hiP, loP);
    // round 1: out -> h_ws (merge emits planes of h2)
    score_topk_kernel<<<sgrid, NTHREADS, 0, stream>>>(hiP, pval, pidx, 8);
    merge_agg_kernel<8><<<BB * TT, NTHREADS, 0, stream>>>(
        out, h_ws, pval, pidx, gain + 1 * DD, bias + 1 * DD, log_mix + 1, log_momentum,
        nullptr, nullptr, hiP, loP);
    // round 2 (fused finalize): h_ws -> out
    score_topk_kernel<<<sgrid, NTHREADS, 0, stream>>>(hiP, pval, pidx, 16);
    merge_agg_kernel<16><<<BB * TT, NTHREADS, 0, stream>>>(
        h_ws, out, pval, pidx, gain + 2 * DD, bias + 2 * DD, log_mix + 2, log_momentum,
        x, log_scale, nullptr, nullptr);
}